// Round 31
// baseline (50.788 us; speedup 1.0000x reference)
//
#include <hip/hip_runtime.h>

// Problem constants (from reference setup_inputs)
#define BZ 4
#define H 192
#define W 640
#define PIX (H * W)            // 122880 pixels per batch
#define MAXINS 200
#define CAND 16
#define CE 36                  // ch*cw
#define CE4 9                  // float4 groups per pixel
#define BATCH_FLOATS (MAXINS * CE)          // 7200 floats per batch
#define BATCH_F4     (BATCH_FLOATS / 4)     // 1800 float4 per batch
#define COMP_FLOATS (BZ * BATCH_FLOATS)     // 28800 floats
#define COMP_BYTES  (COMP_FLOATS * 4)       // 115200 bytes
#define BPB 256                             // blocks per batch (r31: 192->256)
#define NBLK (BZ * BPB)                     // 1024 blocks = exactly 4/CU
#define STRIPE (PIX / BPB)                  // 480 contiguous pixels per block
#define TPB 512                             // threads per block
#define ITEMS 4                             // items per thread (item-major)
#define PARTBF_BYTES ((size_t)NBLK * BATCH_F4 * 8)   // 14.7 MB (bf16x4/item)

// bf16 pack/unpack (RNE)
__device__ __forceinline__ unsigned short f2bf(float f) {
    unsigned u = __float_as_uint(f);
    unsigned r = (u + 0x7FFFu + ((u >> 16) & 1u)) >> 16;
    return (unsigned short)r;
}
__device__ __forceinline__ float bf2f(unsigned short h) {
    return __uint_as_float(((unsigned)h) << 16);
}

// ============ compress: r21 counting sort + item-major gather ============
// r30 (48.15us) = best. Single change this round: BPB 192->256 so the grid
// is 1024 blocks = exactly 4 blocks/CU = 32 waves/CU (vs 24). Compress is
// latency-bound on random L2 loads (~154 in flight/CU); +33% waves should
// raise concurrency proportionally. STRIPE drops to 480 (shorter chains).

__global__ __launch_bounds__(TPB) void compress_sort_kernel(
        const int* __restrict__ inst,
        const float4* __restrict__ compsrc,
        ushort4* __restrict__ partials) {
    __shared__ unsigned char  mloc[STRIPE];     // per-pixel m (cached)
    __shared__ unsigned short sorted[STRIPE];   // local pixel ids, grouped by m
    __shared__ int cnt[MAXINS];
    __shared__ int off[MAXINS + 1];
    __shared__ int off_run[MAXINS];

    const int b    = blockIdx.x / BPB;
    const int blk  = blockIdx.x % BPB;
    const int tid  = threadIdx.x;
    const int pix0 = blk * STRIPE;

    if (tid < MAXINS) cnt[tid] = 0;
    __syncthreads();                             // barrier 1

    // ---- count pass: 480 int LDS atomics, cache m ----
    for (int p = tid; p < STRIPE; p += TPB) {
        int m = inst[b * PIX + pix0 + p];        // coalesced
        mloc[p] = (unsigned char)m;
        atomicAdd(&cnt[m], 1);                   // ds_add_u32
    }
    __syncthreads();                             // barrier 2

    // ---- single-wave exclusive scan (wave 0, shfl, no barriers) ----
    if (tid < 64) {
        const int lane = tid;
        int run = 0;
        #pragma unroll
        for (int c = 0; c < 4; ++c) {            // 4 chunks of 64 bins
            const int idx = c * 64 + lane;       // 0..255
            int v = (idx < MAXINS) ? cnt[idx] : 0;
            const int own = v;
            #pragma unroll
            for (int s = 1; s < 64; s <<= 1) {   // inclusive wave scan
                int u = __shfl_up(v, s);
                if (lane >= s) v += u;
            }
            const int excl = run + v - own;
            if (idx < MAXINS) { off[idx] = excl; off_run[idx] = excl; }
            run += __shfl(v, 63);                // chunk total
        }
        if (lane == 0) off[MAXINS] = STRIPE;
    }
    __syncthreads();                             // barrier 3

    // ---- scatter local pixel ids into m-sorted order ----
    for (int p = tid; p < STRIPE; p += TPB) {
        int slot = atomicAdd(&off_run[mloc[p]], 1);   // ds_add_rtn_u32
        sorted[slot] = (unsigned short)p;
    }
    __syncthreads();                             // barrier 4

    // ---- phase 2: r12-exact item-major register accumulation ----
    const float4* src = compsrc + (size_t)(b * PIX + pix0) * CE4;
    float4 acc[ITEMS];
    int base_[ITEMS], len_[ITEMS], e4_[ITEMS], idx_[ITEMS];
    int maxlen = 0;
    #pragma unroll
    for (int j = 0; j < ITEMS; ++j) {
        const int item = tid + TPB * j;
        acc[j] = make_float4(0.f, 0.f, 0.f, 0.f);
        if (item < BATCH_F4) {
            const int m  = item / CE4;
            e4_[j]   = item - m * CE4;
            base_[j] = off[m];
            len_[j]  = off[m + 1] - off[m];
            maxlen   = len_[j] > maxlen ? len_[j] : maxlen;
        } else { base_[j] = 0; len_[j] = 0; e4_[j] = 0; }
        idx_[j] = (0 < len_[j]) ? (int)sorted[base_[j]] : 0;
    }
    for (int i = 0; i < maxlen; ++i) {
        float4 v[ITEMS];
        #pragma unroll
        for (int j = 0; j < ITEMS; ++j)
            if (i < len_[j]) v[j] = src[(size_t)idx_[j] * CE4 + e4_[j]];
        #pragma unroll
        for (int j = 0; j < ITEMS; ++j)
            idx_[j] = (i + 1 < len_[j]) ? (int)sorted[base_[j] + i + 1] : 0;
        #pragma unroll
        for (int j = 0; j < ITEMS; ++j)
            if (i < len_[j]) {
                acc[j].x += v[j].x; acc[j].y += v[j].y;
                acc[j].z += v[j].z; acc[j].w += v[j].w;
            }
    }

    // ---- store full partial as bf16 (every byte overwritten) ----
    ushort4* p = partials + (size_t)blockIdx.x * BATCH_F4;
    #pragma unroll
    for (int j = 0; j < ITEMS; ++j) {
        const int item = tid + TPB * j;
        if (item < BATCH_F4) {
            ushort4 w;
            w.x = f2bf(acc[j].x); w.y = f2bf(acc[j].y);
            w.z = f2bf(acc[j].z); w.w = f2bf(acc[j].w);
            p[item] = w;                          // coalesced 8B/lane
        }
    }
}

// ============ K2: reduce bf16 partials + sel gather ======================

__global__ void reduce_priv_kernel(const ushort4* __restrict__ partials,
                                   const int* __restrict__ batchidx,
                                   const float4* __restrict__ selsrc,
                                   float4* __restrict__ comp) {
    const int t = blockIdx.x * blockDim.x + threadIdx.x;   // over 7200 float4
    if (t >= COMP_FLOATS / 4) return;
    const int e4 = t % CE4;
    const int bm = t / CE4;
    const int b  = t / BATCH_F4;
    const int j  = t - b * BATCH_F4;
    const int c  = batchidx[bm];
    float4 acc = selsrc[((size_t)bm * CAND + c) * CE4 + e4];
    const ushort4* p = partials + (size_t)b * BPB * BATCH_F4 + j;
    #pragma unroll 8
    for (int s = 0; s < BPB; ++s) {
        ushort4 w = p[(size_t)s * BATCH_F4];
        acc.x += bf2f(w.x); acc.y += bf2f(w.y);
        acc.z += bf2f(w.z); acc.w += bf2f(w.w);
    }
    comp[t] = acc;
}

// ============ fallback (tiny ws): direct atomics =========================

__global__ void init_sel_kernel(const int* __restrict__ batchidx,
                                const float4* __restrict__ selsrc,
                                float4* __restrict__ comp) {
    unsigned t = blockIdx.x * blockDim.x + threadIdx.x;
    if (t >= BZ * MAXINS * CE4) return;
    unsigned e4 = t % CE4;
    unsigned bm = t / CE4;
    int c = batchidx[bm];
    comp[bm * CE4 + e4] = selsrc[(bm * CAND + (unsigned)c) * CE4 + e4];
}

__global__ void compress_direct_kernel(const int* __restrict__ inst,
                                       const float4* __restrict__ compsrc,
                                       float* __restrict__ comp) {
    const unsigned total = BZ * PIX * CE4;
    for (unsigned t = blockIdx.x * blockDim.x + threadIdx.x; t < total;
         t += gridDim.x * blockDim.x) {
        unsigned e4 = t % CE4;
        unsigned pix = t / CE4;
        unsigned b = pix / PIX;
        int m = inst[pix];
        float4 v = compsrc[t];
        float* dst = comp + ((unsigned)(b * MAXINS + m)) * CE + e4 * 4;
        atomicAdd(dst + 0, v.x);
        atomicAdd(dst + 1, v.y);
        atomicAdd(dst + 2, v.z);
        atomicAdd(dst + 3, v.w);
    }
}

// ============ K3: inflate ================================================

__global__ void inflate_kernel(const int* __restrict__ inst,
                               const float4* __restrict__ comp,
                               float4* __restrict__ out) {
    const unsigned total = BZ * PIX * CE4;
    for (unsigned t = blockIdx.x * blockDim.x + threadIdx.x; t < total;
         t += gridDim.x * blockDim.x) {
        unsigned e4 = t % CE4;
        unsigned pix = t / CE4;
        unsigned b = pix / PIX;
        int m = inst[pix];
        out[t] = comp[((unsigned)(b * MAXINS + m)) * CE4 + e4];  // L2-hot gather
    }
}

extern "C" void kernel_launch(void* const* d_in, const int* in_sizes, int n_in,
                              void* d_out, int out_size, void* d_ws, size_t ws_size,
                              hipStream_t stream) {
    const int*    inst     = (const int*)d_in[0];      // (BZ,1,H,W) int32
    const float*  compsrc  = (const float*)d_in[1];    // (BZ,H,W,6,6) f32
    const int*    batchidx = (const int*)d_in[2];      // (BZ,MAXINS) int32
    const float*  selsrc   = (const float*)d_in[3];    // (BZ,MAXINS,CAND,6,6) f32
    float*        out      = (float*)d_out;            // (BZ,H,W,6,6) f32
    float*        comp     = (float*)d_ws;             // 115.2 KB @ ws[0]

    if (ws_size >= (size_t)COMP_BYTES + PARTBF_BYTES) {
        // --- main path: counting-sort compress, bf16 partials, 4 blk/CU ---
        ushort4* partials = (ushort4*)(comp + COMP_FLOATS);
        compress_sort_kernel<<<NBLK, TPB, 0, stream>>>(inst, (const float4*)compsrc,
                                                       partials);
        reduce_priv_kernel<<<(COMP_FLOATS / 4 + 255) / 256, 256, 0, stream>>>(
            partials, batchidx, (const float4*)selsrc, (float4*)comp);
    } else {
        // --- fallback: direct atomics into comp ---
        const int total = BZ * MAXINS * CE4;
        init_sel_kernel<<<(total + 255) / 256, 256, 0, stream>>>(
            batchidx, (const float4*)selsrc, (float4*)comp);
        compress_direct_kernel<<<2048, 256, 0, stream>>>(inst, (const float4*)compsrc,
                                                         comp);
    }

    // K3: inflate comp back to per-pixel output
    inflate_kernel<<<2048, 256, 0, stream>>>(inst, (const float4*)comp, (float4*)out);
}

// Round 32
// 48.657 us; speedup vs baseline: 1.0438x; 1.0438x over previous
//
#include <hip/hip_runtime.h>

// Problem constants (from reference setup_inputs)
#define BZ 4
#define H 192
#define W 640
#define PIX (H * W)            // 122880 pixels per batch
#define MAXINS 200
#define CAND 16
#define CE 36                  // ch*cw
#define CE4 9                  // float4 groups per pixel
#define BATCH_FLOATS (MAXINS * CE)          // 7200 floats per batch
#define BATCH_F4     (BATCH_FLOATS / 4)     // 1800 float4 per batch
#define COMP_FLOATS (BZ * BATCH_FLOATS)     // 28800 floats
#define COMP_BYTES  (COMP_FLOATS * 4)       // 115200 bytes
#define BPB 192                             // blocks per batch (r30 optimum)
#define NBLK (BZ * BPB)                     // 768 compress blocks (3/CU)
#define STRIPE (PIX / BPB)                  // 640 contiguous pixels per block
#define TPB 512                             // threads per block
#define ITEMS 4                             // items per thread (item-major)
#define PARTBF_BYTES ((size_t)NBLK * BATCH_F4 * 8)   // 11.1 MB (bf16x4/item)

// bf16 pack/unpack (RNE)
__device__ __forceinline__ unsigned short f2bf(float f) {
    unsigned u = __float_as_uint(f);
    unsigned r = (u + 0x7FFFu + ((u >> 16) & 1u)) >> 16;
    return (unsigned short)r;
}
__device__ __forceinline__ float bf2f(unsigned short h) {
    return __uint_as_float(((unsigned)h) << 16);
}

// ============ compress: r30 counting sort + item-major gather ============
// Best measured (48.15us total). Occupancy lever closed: 12/24/32 waves
// tested, 24 optimal. This round changes ONLY inflate (LDS-cached).

__global__ __launch_bounds__(TPB) void compress_sort_kernel(
        const int* __restrict__ inst,
        const float4* __restrict__ compsrc,
        ushort4* __restrict__ partials) {
    __shared__ unsigned char  mloc[STRIPE];     // per-pixel m (cached)
    __shared__ unsigned short sorted[STRIPE];   // local pixel ids, grouped by m
    __shared__ int cnt[MAXINS];
    __shared__ int off[MAXINS + 1];
    __shared__ int off_run[MAXINS];

    const int b    = blockIdx.x / BPB;
    const int blk  = blockIdx.x % BPB;
    const int tid  = threadIdx.x;
    const int pix0 = blk * STRIPE;

    if (tid < MAXINS) cnt[tid] = 0;
    __syncthreads();                             // barrier 1

    // ---- count pass: 640 int LDS atomics, cache m ----
    for (int p = tid; p < STRIPE; p += TPB) {
        int m = inst[b * PIX + pix0 + p];        // coalesced
        mloc[p] = (unsigned char)m;
        atomicAdd(&cnt[m], 1);                   // ds_add_u32
    }
    __syncthreads();                             // barrier 2

    // ---- single-wave exclusive scan (wave 0, shfl, no barriers) ----
    if (tid < 64) {
        const int lane = tid;
        int run = 0;
        #pragma unroll
        for (int c = 0; c < 4; ++c) {            // 4 chunks of 64 bins
            const int idx = c * 64 + lane;       // 0..255
            int v = (idx < MAXINS) ? cnt[idx] : 0;
            const int own = v;
            #pragma unroll
            for (int s = 1; s < 64; s <<= 1) {   // inclusive wave scan
                int u = __shfl_up(v, s);
                if (lane >= s) v += u;
            }
            const int excl = run + v - own;
            if (idx < MAXINS) { off[idx] = excl; off_run[idx] = excl; }
            run += __shfl(v, 63);                // chunk total
        }
        if (lane == 0) off[MAXINS] = STRIPE;
    }
    __syncthreads();                             // barrier 3

    // ---- scatter local pixel ids into m-sorted order ----
    for (int p = tid; p < STRIPE; p += TPB) {
        int slot = atomicAdd(&off_run[mloc[p]], 1);   // ds_add_rtn_u32
        sorted[slot] = (unsigned short)p;
    }
    __syncthreads();                             // barrier 4

    // ---- phase 2: r12-exact item-major register accumulation ----
    const float4* src = compsrc + (size_t)(b * PIX + pix0) * CE4;
    float4 acc[ITEMS];
    int base_[ITEMS], len_[ITEMS], e4_[ITEMS], idx_[ITEMS];
    int maxlen = 0;
    #pragma unroll
    for (int j = 0; j < ITEMS; ++j) {
        const int item = tid + TPB * j;
        acc[j] = make_float4(0.f, 0.f, 0.f, 0.f);
        if (item < BATCH_F4) {
            const int m  = item / CE4;
            e4_[j]   = item - m * CE4;
            base_[j] = off[m];
            len_[j]  = off[m + 1] - off[m];
            maxlen   = len_[j] > maxlen ? len_[j] : maxlen;
        } else { base_[j] = 0; len_[j] = 0; e4_[j] = 0; }
        idx_[j] = (0 < len_[j]) ? (int)sorted[base_[j]] : 0;
    }
    for (int i = 0; i < maxlen; ++i) {
        float4 v[ITEMS];
        #pragma unroll
        for (int j = 0; j < ITEMS; ++j)
            if (i < len_[j]) v[j] = src[(size_t)idx_[j] * CE4 + e4_[j]];
        #pragma unroll
        for (int j = 0; j < ITEMS; ++j)
            idx_[j] = (i + 1 < len_[j]) ? (int)sorted[base_[j] + i + 1] : 0;
        #pragma unroll
        for (int j = 0; j < ITEMS; ++j)
            if (i < len_[j]) {
                acc[j].x += v[j].x; acc[j].y += v[j].y;
                acc[j].z += v[j].z; acc[j].w += v[j].w;
            }
    }

    // ---- store full partial as bf16 (every byte overwritten) ----
    ushort4* p = partials + (size_t)blockIdx.x * BATCH_F4;
    #pragma unroll
    for (int j = 0; j < ITEMS; ++j) {
        const int item = tid + TPB * j;
        if (item < BATCH_F4) {
            ushort4 w;
            w.x = f2bf(acc[j].x); w.y = f2bf(acc[j].y);
            w.z = f2bf(acc[j].z); w.w = f2bf(acc[j].w);
            p[item] = w;                          // coalesced 8B/lane
        }
    }
}

// ============ K2: reduce bf16 partials + sel gather ======================

__global__ void reduce_priv_kernel(const ushort4* __restrict__ partials,
                                   const int* __restrict__ batchidx,
                                   const float4* __restrict__ selsrc,
                                   float4* __restrict__ comp) {
    const int t = blockIdx.x * blockDim.x + threadIdx.x;   // over 7200 float4
    if (t >= COMP_FLOATS / 4) return;
    const int e4 = t % CE4;
    const int bm = t / CE4;
    const int b  = t / BATCH_F4;
    const int j  = t - b * BATCH_F4;
    const int c  = batchidx[bm];
    float4 acc = selsrc[((size_t)bm * CAND + c) * CE4 + e4];
    const ushort4* p = partials + (size_t)b * BPB * BATCH_F4 + j;
    #pragma unroll 8
    for (int s = 0; s < BPB; ++s) {
        ushort4 w = p[(size_t)s * BATCH_F4];
        acc.x += bf2f(w.x); acc.y += bf2f(w.y);
        acc.z += bf2f(w.z); acc.w += bf2f(w.w);
    }
    comp[t] = acc;
}

// ============ fallback (tiny ws): direct atomics =========================

__global__ void init_sel_kernel(const int* __restrict__ batchidx,
                                const float4* __restrict__ selsrc,
                                float4* __restrict__ comp) {
    unsigned t = blockIdx.x * blockDim.x + threadIdx.x;
    if (t >= BZ * MAXINS * CE4) return;
    unsigned e4 = t % CE4;
    unsigned bm = t / CE4;
    int c = batchidx[bm];
    comp[bm * CE4 + e4] = selsrc[(bm * CAND + (unsigned)c) * CE4 + e4];
}

__global__ void compress_direct_kernel(const int* __restrict__ inst,
                                       const float4* __restrict__ compsrc,
                                       float* __restrict__ comp) {
    const unsigned total = BZ * PIX * CE4;
    for (unsigned t = blockIdx.x * blockDim.x + threadIdx.x; t < total;
         t += gridDim.x * blockDim.x) {
        unsigned e4 = t % CE4;
        unsigned pix = t / CE4;
        unsigned b = pix / PIX;
        int m = inst[pix];
        float4 v = compsrc[t];
        float* dst = comp + ((unsigned)(b * MAXINS + m)) * CE + e4 * 4;
        atomicAdd(dst + 0, v.x);
        atomicAdd(dst + 1, v.y);
        atomicAdd(dst + 2, v.z);
        atomicAdd(dst + 3, v.w);
    }
}

// ============ K3: inflate via LDS-cached comp slice (single variable) ====
// Removes the per-element L2 gather (~200cyc) from the store path: each
// block stages its batch's 28.8KB comp slice + 640 m-bytes once, then
// streams pure coalesced stores fed from LDS. 29.5KB -> 3 blk/CU, 24 waves.

__global__ __launch_bounds__(TPB) void inflate_lds_kernel(
        const int* __restrict__ inst,
        const float4* __restrict__ comp,
        float4* __restrict__ out) {
    __shared__ float4 lcomp[BATCH_F4];          // 28.8 KB: this batch's comp
    __shared__ unsigned char mloc[STRIPE];

    const int b    = blockIdx.x / BPB;
    const int blk  = blockIdx.x % BPB;
    const int tid  = threadIdx.x;
    const int pix0 = blk * STRIPE;

    for (int i = tid; i < BATCH_F4; i += TPB)
        lcomp[i] = comp[(size_t)b * BATCH_F4 + i];     // L2-hot, coalesced
    for (int p = tid; p < STRIPE; p += TPB)
        mloc[p] = (unsigned char)inst[b * PIX + pix0 + p];
    __syncthreads();

    const size_t base = (size_t)(b * PIX + pix0) * CE4;
    for (int t = tid; t < STRIPE * CE4; t += TPB) {    // 5760 f4 / block
        const int pl = t / CE4;
        const int e4 = t - pl * CE4;
        out[base + t] = lcomp[(int)mloc[pl] * CE4 + e4];  // LDS read, coalesced store
    }
}

extern "C" void kernel_launch(void* const* d_in, const int* in_sizes, int n_in,
                              void* d_out, int out_size, void* d_ws, size_t ws_size,
                              hipStream_t stream) {
    const int*    inst     = (const int*)d_in[0];      // (BZ,1,H,W) int32
    const float*  compsrc  = (const float*)d_in[1];    // (BZ,H,W,6,6) f32
    const int*    batchidx = (const int*)d_in[2];      // (BZ,MAXINS) int32
    const float*  selsrc   = (const float*)d_in[3];    // (BZ,MAXINS,CAND,6,6) f32
    float*        out      = (float*)d_out;            // (BZ,H,W,6,6) f32
    float*        comp     = (float*)d_ws;             // 115.2 KB @ ws[0]

    if (ws_size >= (size_t)COMP_BYTES + PARTBF_BYTES) {
        // --- main path: r30 counting-sort compress, bf16 partials ---
        ushort4* partials = (ushort4*)(comp + COMP_FLOATS);
        compress_sort_kernel<<<NBLK, TPB, 0, stream>>>(inst, (const float4*)compsrc,
                                                       partials);
        reduce_priv_kernel<<<(COMP_FLOATS / 4 + 255) / 256, 256, 0, stream>>>(
            partials, batchidx, (const float4*)selsrc, (float4*)comp);
    } else {
        // --- fallback: direct atomics into comp ---
        const int total = BZ * MAXINS * CE4;
        init_sel_kernel<<<(total + 255) / 256, 256, 0, stream>>>(
            batchidx, (const float4*)selsrc, (float4*)comp);
        compress_direct_kernel<<<2048, 256, 0, stream>>>(inst, (const float4*)compsrc,
                                                         comp);
    }

    // K3: inflate via LDS-cached comp
    inflate_lds_kernel<<<NBLK, TPB, 0, stream>>>(inst, (const float4*)comp,
                                                 (float4*)out);
}